// Round 1
// baseline (361.185 us; speedup 1.0000x reference)
//
#include <hip/hip_runtime.h>
#include <hip/hip_bf16.h>
#include <stdint.h>

#define DIM   1024
#define HEADS 16
#define KVH   4
#define HD    64
#define SEQ   2048
#define BATCH 2
#define MTOT  (BATCH*SEQ)   // 4096

typedef __attribute__((ext_vector_type(8))) short v8s;   // 8 bf16 (4 VGPRs)
typedef __attribute__((ext_vector_type(4))) float v4f;   // MFMA accumulator

static __device__ __forceinline__ short f2bf(float v) {
    __hip_bfloat16 h = __float2bfloat16(v);
    return *reinterpret_cast<short*>(&h);
}

// ---------------- f32 -> bf16 convert (vectorized) ----------------
__global__ __launch_bounds__(256) void k_cvt(const float* __restrict__ in,
                                             short* __restrict__ out, int n4) {
    int i = blockIdx.x * 256 + threadIdx.x;
    if (i >= n4) return;
    float4 v = reinterpret_cast<const float4*>(in)[i];
    short4 o;
    o.x = f2bf(v.x); o.y = f2bf(v.y); o.z = f2bf(v.z); o.w = f2bf(v.w);
    reinterpret_cast<short4*>(out)[i] = o;
}

// ---------------- W [rows][cols] f32 -> Wt [cols][rows] bf16 ----------------
__global__ __launch_bounds__(256) void k_transpose_w(const float* __restrict__ W,
                                                     short* __restrict__ Wt,
                                                     int rows, int cols) {
    __shared__ float tile[32][33];
    int c0 = blockIdx.x * 32, r0 = blockIdx.y * 32;
    int tx = threadIdx.x & 31;
    int ty = threadIdx.x >> 5;        // 0..7
#pragma unroll
    for (int i = 0; i < 4; ++i)
        tile[ty + i*8][tx] = W[(size_t)(r0 + ty + i*8) * cols + c0 + tx];
    __syncthreads();
#pragma unroll
    for (int i = 0; i < 4; ++i)
        Wt[(size_t)(c0 + ty + i*8) * rows + r0 + tx] = f2bf(tile[tx][ty + i*8]);
}

// ---------------- GEMM: C[M][Nout] = A[M][K] * Bt[Nout][K]^T + bias ----------------
// MODE 0: out bf16, remapped to [B][head][n][64] (head = col>>6)
// MODE 1: out f32 row-major [M][Nout]
template<int MODE>
__global__ __launch_bounds__(256)
void k_gemm(const short* __restrict__ A, const short* __restrict__ Bt,
            const float* __restrict__ bias, void* __restrict__ Cout,
            int K, int Nout, int nheads) {
    __shared__ short As[128 * 64];
    __shared__ short Bs[128 * 64];
    const int tid  = threadIdx.x;
    const int lane = tid & 63;
    const int wave = tid >> 6;
    const int bm = blockIdx.x * 128;
    const int bn = blockIdx.y * 128;
    const int wm = (wave >> 1) * 64;
    const int wn = (wave & 1) * 64;
    const int lo = lane & 15, hi = lane >> 4;
    v4f acc[4][4] = {};
    const int nkt = K >> 6;
    for (int kt = 0; kt < nkt; ++kt) {
        __syncthreads();
#pragma unroll
        for (int i = 0; i < 4; ++i) {
            int c = i * 256 + tid;
            int row = c >> 3, col = c & 7;
            int4 va = *reinterpret_cast<const int4*>(A  + (size_t)(bm + row) * K + kt*64 + col*8);
            *reinterpret_cast<int4*>(reinterpret_cast<char*>(As) + row*128 + ((col*16) ^ ((row & 7) << 4))) = va;
            int4 vb = *reinterpret_cast<const int4*>(Bt + (size_t)(bn + row) * K + kt*64 + col*8);
            *reinterpret_cast<int4*>(reinterpret_cast<char*>(Bs) + row*128 + ((col*16) ^ ((row & 7) << 4))) = vb;
        }
        __syncthreads();
#pragma unroll
        for (int ks = 0; ks < 2; ++ks) {
            v8s af[4], bfr[4];
#pragma unroll
            for (int mf = 0; mf < 4; ++mf) {
                int row = wm + mf*16 + lo;
                af[mf] = *reinterpret_cast<const v8s*>(reinterpret_cast<const char*>(As)
                           + row*128 + ((ks*64 + hi*16) ^ ((row & 7) << 4)));
            }
#pragma unroll
            for (int nf = 0; nf < 4; ++nf) {
                int row = wn + nf*16 + lo;
                bfr[nf] = *reinterpret_cast<const v8s*>(reinterpret_cast<const char*>(Bs)
                           + row*128 + ((ks*64 + hi*16) ^ ((row & 7) << 4)));
            }
#pragma unroll
            for (int mf = 0; mf < 4; ++mf)
#pragma unroll
                for (int nf = 0; nf < 4; ++nf)
                    acc[mf][nf] = __builtin_amdgcn_mfma_f32_16x16x32_bf16(af[mf], bfr[nf], acc[mf][nf], 0, 0, 0);
        }
    }
    // epilogue: C/D layout col=lane&15, row=(lane>>4)*4+reg
#pragma unroll
    for (int nf = 0; nf < 4; ++nf) {
        int col = bn + wn + nf*16 + lo;
        float bv = bias[col];
#pragma unroll
        for (int mf = 0; mf < 4; ++mf) {
#pragma unroll
            for (int j = 0; j < 4; ++j) {
                int grow = bm + wm + mf*16 + hi*4 + j;
                float val = acc[mf][nf][j] + bv;
                if (MODE == 0) {
                    int h = col >> 6, d = col & 63;
                    int b = grow >> 11, n = grow & 2047;
                    reinterpret_cast<short*>(Cout)[((size_t)(b * nheads + h) * SEQ + n) * HD + d] = f2bf(val);
                } else {
                    reinterpret_cast<float*>(Cout)[(size_t)grow * Nout + col] = val;
                }
            }
        }
    }
}

// ---------------- flash attention ----------------
// grid: (SEQ/128, BATCH*HEADS). 4 waves x 32 q-rows. KV tile = 32.
__global__ __launch_bounds__(256)
void k_attn(const short* __restrict__ Q, const short* __restrict__ Kh,
            const short* __restrict__ Vh, short* __restrict__ AO) {
    __shared__ short Ks[32 * 64];       // swizzled, rows of 128B
    __shared__ short Vt[64 * 40];       // V^T, padded stride 40 shorts (80B)
    __shared__ short Ps[4][32 * 40];    // per-wave P, padded stride 40
    const int tid  = threadIdx.x;
    const int lane = tid & 63, wave = tid >> 6;
    const int lo = lane & 15, hi = lane >> 4;
    const int bh = blockIdx.y;
    const int b = bh >> 4, h = bh & 15;
    const int kvh = h >> 2;             // KV_GROUPS = 4
    const int qw = blockIdx.x * 128 + wave * 32;
    const short* Qb = Q  + (size_t)(b * HEADS + h)   * SEQ * HD;
    const short* Kb = Kh + (size_t)(b * KVH   + kvh) * SEQ * HD;
    const short* Vb = Vh + (size_t)(b * KVH   + kvh) * SEQ * HD;

    // Q fragments in registers: q rows qw..qw+31, A-layout (m=lane&15, k=8*(lane>>4)+j)
    v8s qf[2][2];
#pragma unroll
    for (int mf = 0; mf < 2; ++mf)
#pragma unroll
        for (int ks = 0; ks < 2; ++ks)
            qf[mf][ks] = *reinterpret_cast<const v8s*>(Qb + (size_t)(qw + mf*16 + lo) * HD + ks*32 + hi*8);

    v4f oacc[2][4] = {};
    float mrun[2][4], lrun[2][4];
#pragma unroll
    for (int mf = 0; mf < 2; ++mf)
#pragma unroll
        for (int j = 0; j < 4; ++j) { mrun[mf][j] = -1e30f; lrun[mf][j] = 0.f; }

    const float scale = 0.125f;         // 64^-0.5
    const int stg_row = tid >> 3;       // 0..31
    const int stg_c   = tid & 7;        // 0..7

    for (int kt = 0; kt < SEQ / 32; ++kt) {
        const int kv0 = kt * 32;
        __syncthreads();                 // previous tile fully consumed
        {   // stage K swizzled + V transposed
            int4 vk = *reinterpret_cast<const int4*>(Kb + (size_t)(kv0 + stg_row) * HD + stg_c*8);
            *reinterpret_cast<int4*>(reinterpret_cast<char*>(Ks)
                + stg_row*128 + ((stg_c*16) ^ ((stg_row & 7) << 4))) = vk;
            int4 vv = *reinterpret_cast<const int4*>(Vb + (size_t)(kv0 + stg_row) * HD + stg_c*8);
            union { int4 q; short s[8]; } u; u.q = vv;
#pragma unroll
            for (int j = 0; j < 8; ++j) Vt[(stg_c*8 + j) * 40 + stg_row] = u.s[j];
        }
        __syncthreads();

        // S = Q K^T  (B-operand = rows of K, since Bt = K)
        v4f s[2][2] = {};
#pragma unroll
        for (int ks = 0; ks < 2; ++ks) {
            v8s kf[2];
#pragma unroll
            for (int nf = 0; nf < 2; ++nf) {
                int row = nf*16 + lo;
                kf[nf] = *reinterpret_cast<const v8s*>(reinterpret_cast<const char*>(Ks)
                           + row*128 + ((ks*64 + hi*16) ^ ((row & 7) << 4)));
            }
#pragma unroll
            for (int mf = 0; mf < 2; ++mf)
#pragma unroll
                for (int nf = 0; nf < 2; ++nf)
                    s[mf][nf] = __builtin_amdgcn_mfma_f32_16x16x32_bf16(qf[mf][ks], kf[nf], s[mf][nf], 0, 0, 0);
        }

        // online softmax; row r=(lane>>4)*4+reg lives in 16 lanes (col=lane&15)
#pragma unroll
        for (int mf = 0; mf < 2; ++mf) {
#pragma unroll
            for (int j = 0; j < 4; ++j) {
                float s0 = s[mf][0][j] * scale, s1 = s[mf][1][j] * scale;
                float v = fmaxf(s0, s1);
                v = fmaxf(v, __shfl_xor(v, 1));
                v = fmaxf(v, __shfl_xor(v, 2));
                v = fmaxf(v, __shfl_xor(v, 4));
                v = fmaxf(v, __shfl_xor(v, 8));
                float mnew = fmaxf(mrun[mf][j], v);
                float sold = __expf(mrun[mf][j] - mnew);
                float p0 = __expf(s0 - mnew);
                float p1 = __expf(s1 - mnew);
                float ls = p0 + p1;
                ls += __shfl_xor(ls, 1);
                ls += __shfl_xor(ls, 2);
                ls += __shfl_xor(ls, 4);
                ls += __shfl_xor(ls, 8);
                lrun[mf][j] = lrun[mf][j] * sold + ls;
                mrun[mf][j] = mnew;
#pragma unroll
                for (int nf = 0; nf < 4; ++nf) oacc[mf][nf][j] *= sold;
                int prow = mf*16 + hi*4 + j;
                Ps[wave][prow*40 + lo]      = f2bf(p0);
                Ps[wave][prow*40 + 16 + lo] = f2bf(p1);
            }
        }

        // O += P V   (A = P from per-wave LDS, B-operand = rows of V^T)
        v8s pa[2], vbf[4];
#pragma unroll
        for (int mf = 0; mf < 2; ++mf)
            pa[mf] = *reinterpret_cast<const v8s*>(reinterpret_cast<const char*>(Ps[wave])
                       + (mf*16 + lo) * 80 + hi*16);
#pragma unroll
        for (int nf = 0; nf < 4; ++nf)
            vbf[nf] = *reinterpret_cast<const v8s*>(reinterpret_cast<const char*>(Vt)
                       + (nf*16 + lo) * 80 + hi*16);
#pragma unroll
        for (int mf = 0; mf < 2; ++mf)
#pragma unroll
            for (int nf = 0; nf < 4; ++nf)
                oacc[mf][nf] = __builtin_amdgcn_mfma_f32_16x16x32_bf16(pa[mf], vbf[nf], oacc[mf][nf], 0, 0, 0);
    }

    // epilogue: write [B][N][H*64] bf16 (A-matrix layout for O-proj)
#pragma unroll
    for (int mf = 0; mf < 2; ++mf) {
#pragma unroll
        for (int j = 0; j < 4; ++j) {
            float rinv = 1.0f / lrun[mf][j];
            int grow = b * SEQ + qw + mf*16 + hi*4 + j;
#pragma unroll
            for (int nf = 0; nf < 4; ++nf) {
                int col = h * HD + nf*16 + lo;
                AO[(size_t)grow * DIM + col] = f2bf(oacc[mf][nf][j] * rinv);
            }
        }
    }
}

extern "C" void kernel_launch(void* const* d_in, const int* in_sizes, int n_in,
                              void* d_out, int out_size, void* d_ws, size_t ws_size,
                              hipStream_t stream) {
    const float* x  = (const float*)d_in[0];
    const float* Wq = (const float*)d_in[1];
    const float* bq = (const float*)d_in[2];
    const float* Wk = (const float*)d_in[3];
    const float* bk = (const float*)d_in[4];
    const float* Wv = (const float*)d_in[5];
    const float* bv = (const float*)d_in[6];
    const float* Wo = (const float*)d_in[7];
    const float* bo = (const float*)d_in[8];
    float* out = (float*)d_out;

    char* w = (char*)d_ws;
    size_t off = 0;
    auto alloc = [&](size_t bytes) { void* p = w + off; off += (bytes + 255) & ~(size_t)255; return p; };
    short* xb  = (short*)alloc((size_t)MTOT * DIM * 2);          // x in bf16
    short* WqT = (short*)alloc((size_t)DIM * DIM * 2);           // [1024][1024]
    short* WkT = (short*)alloc((size_t)(KVH*HD) * DIM * 2);      // [256][1024]
    short* WvT = (short*)alloc((size_t)(KVH*HD) * DIM * 2);
    short* WoT = (short*)alloc((size_t)DIM * DIM * 2);
    short* Qh  = (short*)alloc((size_t)BATCH * HEADS * SEQ * HD * 2);
    short* Kh  = (short*)alloc((size_t)BATCH * KVH   * SEQ * HD * 2);
    short* Vh  = (short*)alloc((size_t)BATCH * KVH   * SEQ * HD * 2);
    short* AO  = (short*)alloc((size_t)MTOT * DIM * 2);          // attention out [B][N][H*D]

    k_cvt<<<dim3((MTOT * DIM / 4 + 255) / 256), dim3(256), 0, stream>>>(x, xb, MTOT * DIM / 4);
    k_transpose_w<<<dim3(DIM/32,      DIM/32), dim3(256), 0, stream>>>(Wq, WqT, DIM, DIM);
    k_transpose_w<<<dim3((KVH*HD)/32, DIM/32), dim3(256), 0, stream>>>(Wk, WkT, DIM, KVH*HD);
    k_transpose_w<<<dim3((KVH*HD)/32, DIM/32), dim3(256), 0, stream>>>(Wv, WvT, DIM, KVH*HD);
    k_transpose_w<<<dim3(DIM/32,      DIM/32), dim3(256), 0, stream>>>(Wo, WoT, DIM, DIM);

    k_gemm<0><<<dim3(MTOT/128, DIM/128),      dim3(256), 0, stream>>>(xb, WqT, bq, (void*)Qh, DIM, DIM,    HEADS);
    k_gemm<0><<<dim3(MTOT/128, (KVH*HD)/128), dim3(256), 0, stream>>>(xb, WkT, bk, (void*)Kh, DIM, KVH*HD, KVH);
    k_gemm<0><<<dim3(MTOT/128, (KVH*HD)/128), dim3(256), 0, stream>>>(xb, WvT, bv, (void*)Vh, DIM, KVH*HD, KVH);

    k_attn<<<dim3(SEQ/128, BATCH*HEADS), dim3(256), 0, stream>>>(Qh, Kh, Vh, AO);

    k_gemm<1><<<dim3(MTOT/128, DIM/128), dim3(256), 0, stream>>>(AO, WoT, bo, (void*)out, DIM, DIM, 0);
}

// Round 4
// 289.511 us; speedup vs baseline: 1.2476x; 1.2476x over previous
//
#include <hip/hip_runtime.h>
#include <hip/hip_bf16.h>
#include <stdint.h>

#define DIM   1024
#define HEADS 16
#define KVH   4
#define HD    64
#define SEQ   2048
#define BATCH 2
#define MTOT  (BATCH*SEQ)   // 4096

// 0.125 (= HD^-0.5) * log2(e): Q is pre-scaled so softmax uses exp2 directly.
#define QSCALE 0.18033688011112042f

typedef __attribute__((ext_vector_type(8)))  short v8s;    // 8 bf16 (4 VGPRs)
typedef __attribute__((ext_vector_type(4)))  float v4f;    // 16x16 accumulator
typedef __attribute__((ext_vector_type(16))) float f32x16; // 32x32 accumulator

static __device__ __forceinline__ short f2bf(float v) {
    __hip_bfloat16 h = __float2bfloat16(v);
    return *reinterpret_cast<short*>(&h);
}

// ---------------- f32 -> bf16 convert (vectorized) ----------------
__global__ __launch_bounds__(256) void k_cvt(const float* __restrict__ in,
                                             short* __restrict__ out, int n4) {
    int i = blockIdx.x * 256 + threadIdx.x;
    if (i >= n4) return;
    float4 v = reinterpret_cast<const float4*>(in)[i];
    short4 o;
    o.x = f2bf(v.x); o.y = f2bf(v.y); o.z = f2bf(v.z); o.w = f2bf(v.w);
    reinterpret_cast<short4*>(out)[i] = o;
}

// ---------------- W [rows][cols] f32 -> Wt [cols][rows] bf16 ----------------
__global__ __launch_bounds__(256) void k_transpose_w(const float* __restrict__ W,
                                                     short* __restrict__ Wt,
                                                     int rows, int cols) {
    __shared__ float tile[32][33];
    int c0 = blockIdx.x * 32, r0 = blockIdx.y * 32;
    int tx = threadIdx.x & 31;
    int ty = threadIdx.x >> 5;        // 0..7
#pragma unroll
    for (int i = 0; i < 4; ++i)
        tile[ty + i*8][tx] = W[(size_t)(r0 + ty + i*8) * cols + c0 + tx];
    __syncthreads();
#pragma unroll
    for (int i = 0; i < 4; ++i)
        Wt[(size_t)(c0 + ty + i*8) * rows + r0 + tx] = f2bf(tile[tx][ty + i*8]);
}

// ---------------- GEMM: C[M][Nout] = A[M][K] * Bt[Nout][K]^T + bias ----------------
// MODE 1: out f32 row-major [M][Nout]                        (O-projection)
// MODE 2: out bf16 V^T: addr ((col>>11)*256 + grow)*2048 + (col&2047), bias1[grow]
// MODE 3: fused Q+K: col<1024 -> Q [b][h][n][64] * QSCALE (bias1);
//                    col>=1024 -> K [b][kvh][n][64] (bias2); K block at +4194304 elems
template<int MODE>
__global__ __launch_bounds__(256)
void k_gemm(const short* __restrict__ A, const short* __restrict__ Bt,
            const float* __restrict__ bias1, const float* __restrict__ bias2,
            void* __restrict__ Cout, int K, int Nout) {
    __shared__ short As[128 * 64];
    __shared__ short Bs[128 * 64];
    const int tid  = threadIdx.x;
    const int lane = tid & 63;
    const int wave = tid >> 6;
    const int bm = blockIdx.x * 128;
    const int bn = blockIdx.y * 128;
    const int wm = (wave >> 1) * 64;
    const int wn = (wave & 1) * 64;
    const int lo = lane & 15, hi = lane >> 4;
    v4f acc[4][4] = {};
    const int nkt = K >> 6;
    for (int kt = 0; kt < nkt; ++kt) {
        __syncthreads();
#pragma unroll
        for (int i = 0; i < 4; ++i) {
            int c = i * 256 + tid;
            int row = c >> 3, col = c & 7;
            int4 va = *reinterpret_cast<const int4*>(A  + (size_t)(bm + row) * K + kt*64 + col*8);
            *reinterpret_cast<int4*>(reinterpret_cast<char*>(As) + row*128 + ((col*16) ^ ((row & 7) << 4))) = va;
            int4 vb = *reinterpret_cast<const int4*>(Bt + (size_t)(bn + row) * K + kt*64 + col*8);
            *reinterpret_cast<int4*>(reinterpret_cast<char*>(Bs) + row*128 + ((col*16) ^ ((row & 7) << 4))) = vb;
        }
        __syncthreads();
#pragma unroll
        for (int ks = 0; ks < 2; ++ks) {
            v8s af[4], bfr[4];
#pragma unroll
            for (int mf = 0; mf < 4; ++mf) {
                int row = wm + mf*16 + lo;
                af[mf] = *reinterpret_cast<const v8s*>(reinterpret_cast<const char*>(As)
                           + row*128 + ((ks*64 + hi*16) ^ ((row & 7) << 4)));
            }
#pragma unroll
            for (int nf = 0; nf < 4; ++nf) {
                int row = wn + nf*16 + lo;
                bfr[nf] = *reinterpret_cast<const v8s*>(reinterpret_cast<const char*>(Bs)
                           + row*128 + ((ks*64 + hi*16) ^ ((row & 7) << 4)));
            }
#pragma unroll
            for (int mf = 0; mf < 4; ++mf)
#pragma unroll
                for (int nf = 0; nf < 4; ++nf)
                    acc[mf][nf] = __builtin_amdgcn_mfma_f32_16x16x32_bf16(af[mf], bfr[nf], acc[mf][nf], 0, 0, 0);
        }
    }
    // epilogue: C/D layout col=lane&15, row=(lane>>4)*4+reg
#pragma unroll
    for (int nf = 0; nf < 4; ++nf) {
        int col = bn + wn + nf*16 + lo;
#pragma unroll
        for (int mf = 0; mf < 4; ++mf) {
#pragma unroll
            for (int j = 0; j < 4; ++j) {
                int grow = bm + wm + mf*16 + hi*4 + j;
                float acv = acc[mf][nf][j];
                if (MODE == 1) {
                    reinterpret_cast<float*>(Cout)[(size_t)grow * Nout + col] = acv + bias1[col];
                } else if (MODE == 2) {
                    // grow = kvh*64+d in [0,256); col = b*2048+n
                    float val = acv + bias1[grow];
                    reinterpret_cast<short*>(Cout)[((size_t)(col >> 11) * 256 + grow) * 2048 + (col & 2047)] = f2bf(val);
                } else { // MODE 3
                    int b = grow >> 11, n = grow & 2047;
                    if (col < 1024) {
                        int hh = col >> 6, d = col & 63;
                        float val = (acv + bias1[col]) * QSCALE;
                        reinterpret_cast<short*>(Cout)[((size_t)(b * HEADS + hh) * SEQ + n) * HD + d] = f2bf(val);
                    } else {
                        int cc = col - 1024;
                        int kvh = cc >> 6, d = cc & 63;
                        float val = acv + bias2[cc];
                        reinterpret_cast<short*>(Cout)[4194304 + ((size_t)(b * KVH + kvh) * SEQ + n) * HD + d] = f2bf(val);
                    }
                }
            }
        }
    }
}

// ---------------- flash attention, swapped-operand, no LDS ----------------
// Grid: 2048 blocks x 64 threads (1 wave). Each wave: 32 q-rows of one (b,h).
// Block id -> (b,kvh) = id&7 so each XCD's resident blocks share one K/V set.
// S^T = K.Q^T via mfma_32x32x16 (A=K, B=Q): C col = q = lane&31 (lane-local q),
// row = kv = (reg&3)+8*(reg>>2)+4*(lane>>5). O^T = V^T.P^T: C col = q again ->
// online-softmax state (m, l) and rescales are pure per-lane scalars.
__global__ __launch_bounds__(64, 4)
void k_attn(const short* __restrict__ Q, const short* __restrict__ K,
            const short* __restrict__ Vt, short* __restrict__ AO) {
    const int lane = threadIdx.x;
    const int l31 = lane & 31, hi2 = lane >> 5;
    const int id  = blockIdx.x;
    const int g   = id & 7;                 // (b, kvh) group -> XCD locality
    const int b   = g >> 2, kvh = g & 3;
    const int idx = id >> 3;                // 0..255
    const int h   = kvh * 4 + (idx >> 6);   // GQA: heads 4k..4k+3 share kv-head k
    const int q0  = (idx & 63) * 32;

    const short* Qb = Q  + ((size_t)(b * HEADS + h) * SEQ + q0) * HD;
    const short* Kb = K  + (size_t)(b * KVH + kvh) * SEQ * HD;
    const short* Vb = Vt + (size_t)(b * KVH + kvh) * HD * SEQ;   // [64 d][2048 n]

    // Q fragments (B-operand): col q = l31, k(d) = 16c + 8*hi2 + j
    v8s qf[4];
#pragma unroll
    for (int c = 0; c < 4; ++c)
        qf[c] = *reinterpret_cast<const v8s*>(Qb + (size_t)l31 * HD + c * 16 + hi2 * 8);

    f32x16 acc0 = {}, acc1 = {};   // O^T rows d 0-31 / 32-63, col q = l31
    float mrun = -1e30f, lsum = 0.f;

    for (int kt = 0; kt < SEQ / 32; ++kt) {
        const short* Kt = Kb + (size_t)kt * 32 * HD;
        f32x16 s = {};
#pragma unroll
        for (int c = 0; c < 4; ++c) {
            v8s kf = *reinterpret_cast<const v8s*>(Kt + (size_t)l31 * HD + c * 16 + hi2 * 8);
            s = __builtin_amdgcn_mfma_f32_32x32x16_bf16(kf, qf[c], s, 0, 0, 0);
        }
        // max over this tile's 32 kv (16 in-lane + cross-half)
        float m0 = fmaxf(fmaxf(s[0],  s[1]),  fmaxf(s[2],  s[3]));
        float m1 = fmaxf(fmaxf(s[4],  s[5]),  fmaxf(s[6],  s[7]));
        float m2 = fmaxf(fmaxf(s[8],  s[9]),  fmaxf(s[10], s[11]));
        float m3 = fmaxf(fmaxf(s[12], s[13]), fmaxf(s[14], s[15]));
        float pmax = fmaxf(fmaxf(m0, m1), fmaxf(m2, m3));
        pmax = fmaxf(pmax, __shfl_xor(pmax, 32));
        // defer-max (T13): only rescale when max grew by > 8 (log2 domain)
        if (!__all(pmax <= mrun + 8.f)) {
            float mnew = fmaxf(mrun, pmax);
            float sc = exp2f(mrun - mnew);
#pragma unroll
            for (int r = 0; r < 16; ++r) { acc0[r] *= sc; acc1[r] *= sc; }
            lsum *= sc;
            mrun = mnew;
        }
#pragma unroll
        for (int r = 0; r < 16; ++r) s[r] = exp2f(s[r] - mrun);   // p in-place
        float a0 = (s[0] + s[1]) + (s[2]  + s[3]);
        float a1 = (s[4] + s[5]) + (s[6]  + s[7]);
        float a2 = (s[8] + s[9]) + (s[10] + s[11]);
        float a3 = (s[12]+ s[13])+ (s[14] + s[15]);
        float ls = (a0 + a1) + (a2 + a3);
        lsum += ls + __shfl_xor(ls, 32);

        // pack p -> bf16 pairs; pk_i = (p[2i] low, p[2i+1] high)
        int pk[8];
#pragma unroll
        for (int i = 0; i < 8; ++i) {
            int r;
            asm("v_cvt_pk_bf16_f32 %0, %1, %2" : "=v"(r) : "v"(s[2*i]), "v"(s[2*i+1]));
            pk[i] = r;
        }
        // half-exchange: B-operand slot j must hold kv = 16*kc + 8*hi2 + j
        int u[8];
#pragma unroll
        for (int i = 0; i < 2; ++i) {
            int p0 = pk[4*i+0], p1 = pk[4*i+1], p2 = pk[4*i+2], p3 = pk[4*i+3];
            int o0 = __shfl_xor(p0, 32), o1 = __shfl_xor(p1, 32);
            int o2 = __shfl_xor(p2, 32), o3 = __shfl_xor(p3, 32);
            u[4*i+0] = hi2 ? o2 : p0;
            u[4*i+1] = hi2 ? o3 : p1;
            u[4*i+2] = hi2 ? p2 : o0;
            u[4*i+3] = hi2 ? p3 : o1;
        }
        union { int i4[4]; v8s v; } pb0, pb1;
        pb0.i4[0] = u[0]; pb0.i4[1] = u[1]; pb0.i4[2] = u[2]; pb0.i4[3] = u[3];
        pb1.i4[0] = u[4]; pb1.i4[1] = u[5]; pb1.i4[2] = u[6]; pb1.i4[3] = u[7];

        // O^T += V^T-chunk . P^T   (A row = d = lane&31, k = kv = 8*hi2+j)
        const short* Vtt = Vb + kt * 32;
        {
            v8s vf0 = *reinterpret_cast<const v8s*>(Vtt + (size_t)l31        * SEQ + hi2 * 8);
            acc0 = __builtin_amdgcn_mfma_f32_32x32x16_bf16(vf0, pb0.v, acc0, 0, 0, 0);
            v8s vf1 = *reinterpret_cast<const v8s*>(Vtt + (size_t)(32 + l31) * SEQ + hi2 * 8);
            acc1 = __builtin_amdgcn_mfma_f32_32x32x16_bf16(vf1, pb0.v, acc1, 0, 0, 0);
            v8s vf2 = *reinterpret_cast<const v8s*>(Vtt + (size_t)l31        * SEQ + 16 + hi2 * 8);
            acc0 = __builtin_amdgcn_mfma_f32_32x32x16_bf16(vf2, pb1.v, acc0, 0, 0, 0);
            v8s vf3 = *reinterpret_cast<const v8s*>(Vtt + (size_t)(32 + l31) * SEQ + 16 + hi2 * 8);
            acc1 = __builtin_amdgcn_mfma_f32_32x32x16_bf16(vf3, pb1.v, acc1, 0, 0, 0);
        }
    }

    // epilogue: lane holds q = q0+l31; d = 32*mt + 8*rg + 4*hi2 + i
    float rinv = 1.f / lsum;
    short* Ao = AO + ((size_t)(b * SEQ + q0 + l31)) * DIM + h * HD;
#pragma unroll
    for (int rg = 0; rg < 4; ++rg) {
        short4 st0, st1;
        st0.x = f2bf(acc0[rg*4+0] * rinv); st0.y = f2bf(acc0[rg*4+1] * rinv);
        st0.z = f2bf(acc0[rg*4+2] * rinv); st0.w = f2bf(acc0[rg*4+3] * rinv);
        *reinterpret_cast<short4*>(Ao + rg*8 + hi2*4) = st0;
        st1.x = f2bf(acc1[rg*4+0] * rinv); st1.y = f2bf(acc1[rg*4+1] * rinv);
        st1.z = f2bf(acc1[rg*4+2] * rinv); st1.w = f2bf(acc1[rg*4+3] * rinv);
        *reinterpret_cast<short4*>(Ao + 32 + rg*8 + hi2*4) = st1;
    }
}

extern "C" void kernel_launch(void* const* d_in, const int* in_sizes, int n_in,
                              void* d_out, int out_size, void* d_ws, size_t ws_size,
                              hipStream_t stream) {
    const float* x  = (const float*)d_in[0];
    const float* Wq = (const float*)d_in[1];
    const float* bq = (const float*)d_in[2];
    const float* Wk = (const float*)d_in[3];
    const float* bk = (const float*)d_in[4];
    const float* Wv = (const float*)d_in[5];
    const float* bv = (const float*)d_in[6];
    const float* Wo = (const float*)d_in[7];
    const float* bo = (const float*)d_in[8];
    float* out = (float*)d_out;

    char* w = (char*)d_ws;
    size_t off = 0;
    auto alloc = [&](size_t bytes) { void* p = w + off; off += (bytes + 255) & ~(size_t)255; return p; };
    short* xb   = (short*)alloc((size_t)MTOT * DIM * 2);           // x bf16
    short* WqkT = (short*)alloc((size_t)(DIM + KVH*HD) * DIM * 2); // [1280][1024]
    short* WvT  = (short*)alloc((size_t)(KVH*HD) * DIM * 2);       // [256][1024]
    short* WoT  = (short*)alloc((size_t)DIM * DIM * 2);
    short* QK   = (short*)alloc((size_t)(BATCH*HEADS*SEQ*HD + BATCH*KVH*SEQ*HD) * 2); // Q then K
    short* VtG  = (short*)alloc((size_t)BATCH * KVH * HD * SEQ * 2); // V^T [b][kvh*64+d][n]
    short* AO   = (short*)alloc((size_t)MTOT * DIM * 2);           // attn out [B][N][H*D]

    short* Qh = QK;
    short* Kh = QK + (size_t)BATCH * HEADS * SEQ * HD;  // == QK + 4194304

    k_cvt<<<dim3((MTOT * DIM / 4 + 255) / 256), dim3(256), 0, stream>>>(x, xb, MTOT * DIM / 4);
    k_transpose_w<<<dim3(DIM/32,      DIM/32), dim3(256), 0, stream>>>(Wq, WqkT,             DIM, DIM);
    k_transpose_w<<<dim3((KVH*HD)/32, DIM/32), dim3(256), 0, stream>>>(Wk, WqkT + DIM*DIM,   DIM, KVH*HD);
    k_transpose_w<<<dim3((KVH*HD)/32, DIM/32), dim3(256), 0, stream>>>(Wv, WvT,              DIM, KVH*HD);
    k_transpose_w<<<dim3(DIM/32,      DIM/32), dim3(256), 0, stream>>>(Wo, WoT,              DIM, DIM);

    // fused Q+K projection (Nout = 1280)
    k_gemm<3><<<dim3(MTOT/128, (DIM + KVH*HD)/128), dim3(256), 0, stream>>>(
        xb, WqkT, bq, bk, (void*)QK, DIM, DIM + KVH*HD);
    // V^T = Wv^T . x^T  (M=256, N=4096) — emits V already transposed
    k_gemm<2><<<dim3((KVH*HD)/128, MTOT/128), dim3(256), 0, stream>>>(
        WvT, xb, bv, nullptr, (void*)VtG, DIM, MTOT);

    // one block per (b, h, 32-row q-tile): 2*16*64 = 2048 blocks
    k_attn<<<dim3(BATCH * HEADS * (SEQ/32)), dim3(64), 0, stream>>>(Qh, Kh, VtG, AO);

    k_gemm<1><<<dim3(MTOT/128, DIM/128), dim3(256), 0, stream>>>(
        AO, WoT, bo, nullptr, (void*)out, DIM, DIM);
}